// Round 1
// baseline (152.533 us; speedup 1.0000x reference)
//
#include <hip/hip_runtime.h>
#include <math.h>

#define N_  32
#define C_  512
#define P_  1024
#define KG_ 10
#define KV_ 8

// ---------------------------------------------------------------------------
// Kernel A: logits = x^T W + b, softmax over 10 clusters, store a[n][k<8][p].
// Grid: N*8 blocks of 256 threads. Each block: 128 p's, c-reduction split in
// half across thread groups (ch=0: c 0..255, ch=1: c 256..511), combined via
// LDS. 4 waves/CU on a 256-block grid -> latency hiding for the HBM stream.
// ---------------------------------------------------------------------------
__global__ __launch_bounds__(256) void vlad_softmax(
    const float* __restrict__ x, const float* __restrict__ w,
    const float* __restrict__ bias, float* __restrict__ a_ws) {
  __shared__ float part[128][KG_];   // 5 KiB
  const int n  = blockIdx.x >> 3;
  const int pl = threadIdx.x & 127;
  const int ch = threadIdx.x >> 7;     // which c-half this thread reduces
  const int p  = (blockIdx.x & 7) * 128 + pl;

  const float* xp = x + ((size_t)n * C_ + ch * 256) * P_ + p;
  const float* wp = w + ch * 256;

  float acc[KG_];
#pragma unroll
  for (int k = 0; k < KG_; ++k) acc[k] = 0.f;

#pragma unroll 2
  for (int c = 0; c < 256; c += 8) {
    float xv[8];
#pragma unroll
    for (int j = 0; j < 8; ++j) xv[j] = xp[(c + j) * P_];   // coalesced over p
#pragma unroll
    for (int k = 0; k < KG_; ++k) {
      // block-uniform addresses -> s_load_dwordx4 from scalar cache
      float4 wa = *reinterpret_cast<const float4*>(wp + k * C_ + c);
      float4 wb = *reinterpret_cast<const float4*>(wp + k * C_ + c + 4);
      acc[k] += xv[0] * wa.x + xv[1] * wa.y + xv[2] * wa.z + xv[3] * wa.w
              + xv[4] * wb.x + xv[5] * wb.y + xv[6] * wb.z + xv[7] * wb.w;
    }
  }

  if (ch == 1) {
#pragma unroll
    for (int k = 0; k < KG_; ++k) part[pl][k] = acc[k];
  }
  __syncthreads();
  if (ch == 0) {
    float l[KG_];
    float m = -1e30f;
#pragma unroll
    for (int k = 0; k < KG_; ++k) {
      l[k] = acc[k] + part[pl][k] + bias[k];
      m = fmaxf(m, l[k]);
    }
    float sum = 0.f;
#pragma unroll
    for (int k = 0; k < KG_; ++k) { l[k] = __expf(l[k] - m); sum += l[k]; }
    const float inv = 1.f / sum;
#pragma unroll
    for (int k = 0; k < KV_; ++k)
      a_ws[((size_t)n * KV_ + k) * P_ + p] = l[k] * inv;   // coalesced
  }
}

// ---------------------------------------------------------------------------
// Kernel B: ax[n][k][c] = sum_p a[n][k][p] * x[n][c][p]  (k < 8 only).
// Grid: N*32 blocks of 256 threads. Block covers 16 c's; each wave owns 4 c's
// exclusively (no cross-wave combine). Lanes over p (float4, coalesced).
// In-wave reduction: split-butterfly — 32 values reduced with 32 shuffles.
// ---------------------------------------------------------------------------
__global__ __launch_bounds__(256) void vlad_ax(
    const float* __restrict__ x, const float* __restrict__ a_ws,
    float* __restrict__ ax_ws) {
  const int n    = blockIdx.x >> 5;
  const int cb   = blockIdx.x & 31;
  const int lane = threadIdx.x & 63;
  const int wv   = threadIdx.x >> 6;
  const int c0   = cb * 16 + wv * 4;

  const float* ap = a_ws + (size_t)n * KV_ * P_;
  const float* xp = x + (size_t)n * C_ * P_;

  float acc[4][8];
#pragma unroll
  for (int cc = 0; cc < 4; ++cc)
#pragma unroll
    for (int k = 0; k < 8; ++k) acc[cc][k] = 0.f;

#pragma unroll
  for (int i = 0; i < 4; ++i) {
    const int pb = i * 256 + lane * 4;
    float4 a4[8];
#pragma unroll
    for (int k = 0; k < 8; ++k)
      a4[k] = *reinterpret_cast<const float4*>(ap + (size_t)k * P_ + pb);
#pragma unroll
    for (int cc = 0; cc < 4; ++cc) {
      float4 x4 = *reinterpret_cast<const float4*>(xp + (size_t)(c0 + cc) * P_ + pb);
#pragma unroll
      for (int k = 0; k < 8; ++k)
        acc[cc][k] += x4.x * a4[k].x + x4.y * a4[k].y
                    + x4.z * a4[k].z + x4.w * a4[k].w;
    }
  }

  // Pack 32 partials, reduce across 64 lanes with value-splitting butterfly.
  float v[32];
#pragma unroll
  for (int cc = 0; cc < 4; ++cc)
#pragma unroll
    for (int k = 0; k < 8; ++k) v[cc * 8 + k] = acc[cc][k];

  {  // step mask=1, keep 16
    const bool hi = lane & 1;
#pragma unroll
    for (int j = 0; j < 16; ++j) {
      float send = hi ? v[j] : v[j + 16];
      float keep = hi ? v[j + 16] : v[j];
      v[j] = keep + __shfl_xor(send, 1, 64);
    }
  }
  {  // mask=2, keep 8
    const bool hi = lane & 2;
#pragma unroll
    for (int j = 0; j < 8; ++j) {
      float send = hi ? v[j] : v[j + 8];
      float keep = hi ? v[j + 8] : v[j];
      v[j] = keep + __shfl_xor(send, 2, 64);
    }
  }
  {  // mask=4, keep 4
    const bool hi = lane & 4;
#pragma unroll
    for (int j = 0; j < 4; ++j) {
      float send = hi ? v[j] : v[j + 4];
      float keep = hi ? v[j + 4] : v[j];
      v[j] = keep + __shfl_xor(send, 4, 64);
    }
  }
  {  // mask=8, keep 2
    const bool hi = lane & 8;
#pragma unroll
    for (int j = 0; j < 2; ++j) {
      float send = hi ? v[j] : v[j + 2];
      float keep = hi ? v[j + 2] : v[j];
      v[j] = keep + __shfl_xor(send, 8, 64);
    }
  }
  {  // mask=16, keep 1
    const bool hi = lane & 16;
    float send = hi ? v[0] : v[1];
    float keep = hi ? v[1] : v[0];
    v[0] = keep + __shfl_xor(send, 16, 64);
  }
  v[0] += __shfl_xor(v[0], 32, 64);

  if (lane < 32) {
    // lane bit s selected original-index bit (4-s): o = bitrev5(lane)
    const int o = ((lane & 1) << 4) | ((lane & 2) << 2) | (lane & 4)
                | (((lane >> 3) & 1) << 1) | ((lane >> 4) & 1);
    const int cc = o >> 3;
    const int k  = o & 7;
    ax_ws[((size_t)n * KV_ + k) * C_ + (c0 + cc)] = v[0];
  }
}

// ---------------------------------------------------------------------------
// Kernel C: a_sum, residual vs centers, L2 normalize, write out.
// Grid: N*8 blocks (one per (n,k)), 256 threads.
// ---------------------------------------------------------------------------
__global__ __launch_bounds__(256) void vlad_final(
    const float* __restrict__ a_ws, const float* __restrict__ ax_ws,
    const float* __restrict__ centers, float* __restrict__ out) {
  __shared__ float sbuf[8];
  const int n = blockIdx.x >> 3;
  const int k = blockIdx.x & 7;
  const int tid = threadIdx.x, lane = tid & 63, wv = tid >> 6;

  // a_sum = sum_p a[n][k][p]
  float4 av = *reinterpret_cast<const float4*>(a_ws + ((size_t)n * KV_ + k) * P_ + tid * 4);
  float s = (av.x + av.y) + (av.z + av.w);
#pragma unroll
  for (int d = 1; d < 64; d <<= 1) s += __shfl_xor(s, d, 64);
  if (lane == 0) sbuf[wv] = s;
  __syncthreads();
  const float a_sum = (sbuf[0] + sbuf[1]) + (sbuf[2] + sbuf[3]);

  const int c = tid * 2;
  const size_t base = ((size_t)n * KV_ + k) * C_;
  float r0 = ax_ws[base + c]     - a_sum * centers[k * C_ + c];
  float r1 = ax_ws[base + c + 1] - a_sum * centers[k * C_ + c + 1];

  float ss = r0 * r0 + r1 * r1;
#pragma unroll
  for (int d = 1; d < 64; d <<= 1) ss += __shfl_xor(ss, d, 64);
  if (lane == 0) sbuf[4 + wv] = ss;
  __syncthreads();
  const float norm2 = (sbuf[4] + sbuf[5]) + (sbuf[6] + sbuf[7]);
  const float inv = 1.f / fmaxf(sqrtf(norm2), 1e-12f);

  out[(size_t)n * (KV_ * C_) + k * C_ + c]     = r0 * inv;
  out[(size_t)n * (KV_ * C_) + k * C_ + c + 1] = r1 * inv;
}

extern "C" void kernel_launch(void* const* d_in, const int* in_sizes, int n_in,
                              void* d_out, int out_size, void* d_ws, size_t ws_size,
                              hipStream_t stream) {
  const float* x       = (const float*)d_in[0];
  const float* conv_w  = (const float*)d_in[1];
  const float* conv_b  = (const float*)d_in[2];
  const float* centers = (const float*)d_in[3];
  float* out = (float*)d_out;

  float* a_ws  = (float*)d_ws;                 // N*KV*P floats = 1 MiB
  float* ax_ws = a_ws + (size_t)N_ * KV_ * P_; // N*KV*C floats = 512 KiB

  hipLaunchKernelGGL(vlad_softmax, dim3(N_ * 8),  dim3(256), 0, stream,
                     x, conv_w, conv_b, a_ws);
  hipLaunchKernelGGL(vlad_ax,      dim3(N_ * 32), dim3(256), 0, stream,
                     x, a_ws, ax_ws);
  hipLaunchKernelGGL(vlad_final,   dim3(N_ * 8),  dim3(256), 0, stream,
                     a_ws, ax_ws, centers, out);
}

// Round 2
// 126.618 us; speedup vs baseline: 1.2047x; 1.2047x over previous
//
#include <hip/hip_runtime.h>
#include <math.h>

#define N_   32
#define C_   512
#define P_   1024
#define KG_  10
#define KV_  8
#define PT_  16            // p rows per LDS tile
#define TILES_ 4           // tiles per block -> 64 p per block
#define PB_  (PT_ * TILES_)
#define NBLK_P 16          // P_ / PB_
#define XS_  513           // xt row stride in floats (conflict-free: bank = (p + c) & 31)

// ---------------------------------------------------------------------------
// Fused kernel: per (n, 64-p chunk): stage x tiles in LDS, compute logits ->
// softmax -> partial ax / partial a_sum. x is read from HBM exactly once.
// Grid: N*16 = 512 blocks of 256 threads (4 waves).
// ---------------------------------------------------------------------------
__global__ __launch_bounds__(256) void vlad_fused(
    const float* __restrict__ x, const float* __restrict__ w,
    const float* __restrict__ bias,
    float* __restrict__ part_ax, float* __restrict__ asum_part) {
  __shared__ __align__(16) float xt[PT_ * XS_];    // 32832 B  [p][c] stride 513
  __shared__ __align__(16) float part[160 * 20];   // 12800 B  [wv*40+pj*10+k][col]
  __shared__ __align__(16) float lg[PT_ * KG_];    // logits [p][k]
  __shared__ __align__(16) float a_l[PT_ * KV_];   // softmax weights [p][k<8]

  const int t    = threadIdx.x;
  const int lane = t & 63;
  const int wv   = t >> 6;
  const int n    = blockIdx.x >> 4;
  const int pb   = blockIdx.x & 15;

  const float* xn = x + (size_t)n * C_ * P_;

  float acc2[2][KV_];     // ax partials for c = t and c = t + 256
#pragma unroll
  for (int k = 0; k < KV_; ++k) { acc2[0][k] = 0.f; acc2[1][k] = 0.f; }
  float asum[KV_];        // block-partial a_sum (thread 0's copy is stored)
#pragma unroll
  for (int k = 0; k < KV_; ++k) asum[k] = 0.f;

  for (int tt = 0; tt < TILES_; ++tt) {
    const int gp = pb * PB_ + tt * PT_;

    __syncthreads();   // xt readers of previous tile must be done

    // ---- P1: global -> LDS, 16 p x 512 c (64 B per c-row, coalesced) ----
#pragma unroll
    for (int j = 0; j < 8; ++j) {
      const int lid = j * 256 + t;
      const int c   = lid >> 2;
      const int p4  = (lid & 3) * 4;
      const float4 v =
          *reinterpret_cast<const float4*>(xn + (size_t)c * P_ + gp + p4);
      xt[(p4 + 0) * XS_ + c] = v.x;
      xt[(p4 + 1) * XS_ + c] = v.y;
      xt[(p4 + 2) * XS_ + c] = v.z;
      xt[(p4 + 3) * XS_ + c] = v.w;
    }
    __syncthreads();

    // ---- P2: logits[p][k] = sum_c x[p][c] * w[k][c] ----
    // wave wv owns p rows {wv*4 .. wv*4+3}; lane <-> c slice.
    float acc[4][KG_];
#pragma unroll
    for (int pj = 0; pj < 4; ++pj)
#pragma unroll
      for (int k = 0; k < KG_; ++k) acc[pj][k] = 0.f;

#pragma unroll 2
    for (int cb = 0; cb < 8; ++cb) {
      const int c = cb * 64 + lane;
      float wreg[KG_];
#pragma unroll
      for (int k = 0; k < KG_; ++k) wreg[k] = w[k * C_ + c];  // L1-hot, coalesced
#pragma unroll
      for (int pj = 0; pj < 4; ++pj) {
        const float xv = xt[(wv * 4 + pj) * XS_ + c];
#pragma unroll
        for (int k = 0; k < KG_; ++k) acc[pj][k] += xv * wreg[k];
      }
    }
    // quad reduce (sum over lane XOR {1,2}) -> 16 partial columns per value
#pragma unroll
    for (int pj = 0; pj < 4; ++pj) {
#pragma unroll
      for (int k = 0; k < KG_; ++k) {
        float v = acc[pj][k];
        v += __shfl_xor(v, 1, 64);
        v += __shfl_xor(v, 2, 64);
        if ((lane & 3) == 0)
          part[(wv * 40 + pj * 10 + k) * 20 + (lane >> 2)] = v;
      }
    }
    __syncthreads();

    // combine the 16 columns; rows: r = wv*40 + pj*10 + k
    if (t < 160) {
      const float* row = &part[t * 20];
      const float4 s0 = *reinterpret_cast<const float4*>(row);
      const float4 s1 = *reinterpret_cast<const float4*>(row + 4);
      const float4 s2 = *reinterpret_cast<const float4*>(row + 8);
      const float4 s3 = *reinterpret_cast<const float4*>(row + 12);
      const float s = ((s0.x + s0.y) + (s0.z + s0.w)) +
                      ((s1.x + s1.y) + (s1.z + s1.w)) +
                      ((s2.x + s2.y) + (s2.z + s2.w)) +
                      ((s3.x + s3.y) + (s3.z + s3.w));
      const int k = t % 10;
      const int p = (t / 40) * 4 + (t % 40) / 10;
      lg[p * KG_ + k] = s + bias[k];
    }
    __syncthreads();

    // softmax over 10 clusters, keep k<8; accumulate block a_sum partials
    if (t < PT_) {
      float l[KG_];
      float m = -1e30f;
#pragma unroll
      for (int k = 0; k < KG_; ++k) {
        l[k] = lg[t * KG_ + k];
        m = fmaxf(m, l[k]);
      }
      float sum = 0.f;
#pragma unroll
      for (int k = 0; k < KG_; ++k) { l[k] = __expf(l[k] - m); sum += l[k]; }
      const float inv = 1.f / sum;
#pragma unroll
      for (int k = 0; k < KV_; ++k) {
        const float a = l[k] * inv;
        a_l[t * KV_ + k] = a;
        float s = a;                       // reduce over p (lanes 0..15)
        s += __shfl_xor(s, 1, 64);
        s += __shfl_xor(s, 2, 64);
        s += __shfl_xor(s, 4, 64);
        s += __shfl_xor(s, 8, 64);
        asum[k] += s;
      }
    }
    __syncthreads();

    // ---- P3: ax[k][c] partial accumulation; lane <-> c (t and t+256) ----
#pragma unroll 4
    for (int p = 0; p < PT_; ++p) {
      const float4 a0 = *reinterpret_cast<const float4*>(&a_l[p * KV_]);
      const float4 a1 = *reinterpret_cast<const float4*>(&a_l[p * KV_ + 4]);
      const float x0 = xt[p * XS_ + t];
      const float x1 = xt[p * XS_ + t + 256];
      acc2[0][0] += a0.x * x0;  acc2[1][0] += a0.x * x1;
      acc2[0][1] += a0.y * x0;  acc2[1][1] += a0.y * x1;
      acc2[0][2] += a0.z * x0;  acc2[1][2] += a0.z * x1;
      acc2[0][3] += a0.w * x0;  acc2[1][3] += a0.w * x1;
      acc2[0][4] += a1.x * x0;  acc2[1][4] += a1.x * x1;
      acc2[0][5] += a1.y * x0;  acc2[1][5] += a1.y * x1;
      acc2[0][6] += a1.z * x0;  acc2[1][6] += a1.z * x1;
      acc2[0][7] += a1.w * x0;  acc2[1][7] += a1.w * x1;
    }
  }

  // write per-block partials
  const size_t base = (size_t)(n * NBLK_P + pb) * KV_ * C_;
#pragma unroll
  for (int k = 0; k < KV_; ++k) {
    part_ax[base + k * C_ + t]       = acc2[0][k];
    part_ax[base + k * C_ + t + 256] = acc2[1][k];
  }
  if (t == 0) {
#pragma unroll
    for (int k = 0; k < KV_; ++k)
      asum_part[(n * NBLK_P + pb) * KV_ + k] = asum[k];
  }
}

// ---------------------------------------------------------------------------
// Reducer: sum 16 block-partials, residual vs centers, L2 normalize, write.
// Grid: N*8 blocks (one per (n,k)) of 256 threads.
// ---------------------------------------------------------------------------
__global__ __launch_bounds__(256) void vlad_reduce(
    const float* __restrict__ part_ax, const float* __restrict__ asum_part,
    const float* __restrict__ centers, float* __restrict__ out) {
  __shared__ float sred[4];
  const int n = blockIdx.x >> 3;
  const int k = blockIdx.x & 7;
  const int t = threadIdx.x, lane = t & 63, wv = t >> 6;

  float s0 = 0.f, s1 = 0.f, asv = 0.f;
#pragma unroll
  for (int b = 0; b < NBLK_P; ++b) {
    const size_t base = ((size_t)(n * NBLK_P + b) * KV_ + k) * C_;
    s0  += part_ax[base + t];
    s1  += part_ax[base + t + 256];
    asv += asum_part[(n * NBLK_P + b) * KV_ + k];
  }
  const float r0 = s0 - asv * centers[k * C_ + t];
  const float r1 = s1 - asv * centers[k * C_ + t + 256];

  float ss = r0 * r0 + r1 * r1;
#pragma unroll
  for (int d = 1; d < 64; d <<= 1) ss += __shfl_xor(ss, d, 64);
  if (lane == 0) sred[wv] = ss;
  __syncthreads();
  const float tot = (sred[0] + sred[1]) + (sred[2] + sred[3]);
  const float inv = 1.f / fmaxf(sqrtf(tot), 1e-12f);

  out[(size_t)n * (KV_ * C_) + k * C_ + t]       = r0 * inv;
  out[(size_t)n * (KV_ * C_) + k * C_ + t + 256] = r1 * inv;
}

extern "C" void kernel_launch(void* const* d_in, const int* in_sizes, int n_in,
                              void* d_out, int out_size, void* d_ws, size_t ws_size,
                              hipStream_t stream) {
  const float* x       = (const float*)d_in[0];
  const float* conv_w  = (const float*)d_in[1];
  const float* conv_b  = (const float*)d_in[2];
  const float* centers = (const float*)d_in[3];
  float* out = (float*)d_out;

  float* part_ax   = (float*)d_ws;                                  // 8 MiB
  float* asum_part = part_ax + (size_t)N_ * NBLK_P * KV_ * C_;      // 16 KiB

  hipLaunchKernelGGL(vlad_fused, dim3(N_ * NBLK_P), dim3(256), 0, stream,
                     x, conv_w, conv_b, part_ax, asum_part);
  hipLaunchKernelGGL(vlad_reduce, dim3(N_ * KV_), dim3(256), 0, stream,
                     part_ax, asum_part, centers, out);
}